// Round 1
// baseline (269.761 us; speedup 1.0000x reference)
//
#include <hip/hip_runtime.h>

#define NDATA 262144
#define SD 8
#define HL 16
#define NN 16
#define ROWLEN (SD * (1 + NN))   // 136 floats per input row

// One 16-lane group per data row; lane j handles neighbor j.
// Phi weights are read with wave-uniform compile-time indices -> scalar loads.
__global__ __launch_bounds__(256) void deepset_kernel(
    const float* __restrict__ x,
    const float* __restrict__ phi_w1, const float* __restrict__ phi_b1,
    const float* __restrict__ phi_w2, const float* __restrict__ phi_b2,
    const float* __restrict__ rho_w1, const float* __restrict__ rho_b1,
    const float* __restrict__ rho_w2, const float* __restrict__ rho_b2,
    float* __restrict__ out)
{
    const int tid = blockIdx.x * blockDim.x + threadIdx.x;
    const int row = tid >> 4;        // data row handled by this 16-lane group
    const int j   = tid & 15;        // neighbor index = lane-in-group
    const float* __restrict__ xr = x + (long)row * ROWLEN;

    // ---- load this lane's neighbor feature vector
    // nb[d] = x[row, SD + d*NN + j] : for fixed d, lanes j=0..15 read 16
    // consecutive floats -> coalesced.
    float nb[SD];
#pragma unroll
    for (int d = 0; d < SD; ++d)
        nb[d] = xr[SD + d * NN + j];

    // ---- phi layer 1: 32 outputs (weights via scalar loads, FMA v,s,v)
    float h1[32];
#pragma unroll
    for (int o = 0; o < 32; ++o) {
        float acc = phi_b1[o];
#pragma unroll
        for (int d = 0; d < SD; ++d)
            acc = fmaf(phi_w1[o * SD + d], nb[d], acc);
        h1[o] = fmaxf(acc, 0.0f);
    }

    // ---- phi layer 2: 16 outputs
    float h2[HL];
#pragma unroll
    for (int k = 0; k < HL; ++k) {
        float acc = phi_b2[k];
#pragma unroll
        for (int o = 0; o < 32; ++o)
            acc = fmaf(phi_w2[k * 32 + o], h1[o], acc);
        h2[k] = fmaxf(acc, 0.0f);
    }

    // ---- sum over the 16 neighbors: butterfly within the 16-lane group.
    // xor masks 1,2,4,8 stay inside the group on the 64-wide wave.
#pragma unroll
    for (int k = 0; k < HL; ++k) {
#pragma unroll
        for (int m = 1; m < 16; m <<= 1)
            h2[k] += __shfl_xor(h2[k], m);
    }
    // h2[k] now = summ[k] in every lane of the group.

    // ---- rho layer 1: 32 outputs distributed 2 per lane (o = 2j, 2j+1).
    // Weight rows 2j,2j+1 are 48 contiguous floats at rho_w1 + 48*j -> coalesced.
    const int o0 = 2 * j;
    float y0 = rho_b1[o0 + 0];
    float y1 = rho_b1[o0 + 1];
    const float* __restrict__ w0 = rho_w1 + (o0 + 0) * (SD + HL);
    const float* __restrict__ w1 = rho_w1 + (o0 + 1) * (SD + HL);
#pragma unroll
    for (int d = 0; d < SD; ++d) {
        const float sv = xr[d];          // broadcast within group (L1 hit)
        y0 = fmaf(w0[d], sv, y0);
        y1 = fmaf(w1[d], sv, y1);
    }
#pragma unroll
    for (int k = 0; k < HL; ++k) {
        y0 = fmaf(w0[SD + k], h2[k], y0);
        y1 = fmaf(w1[SD + k], h2[k], y1);
    }
    y0 = fmaxf(y0, 0.0f);
    y1 = fmaxf(y1, 0.0f);

    // ---- rho layer 2: per-lane partial products, reduce over the group.
    float p0 = fmaf(rho_w2[0 * 32 + o0], y0, rho_w2[0 * 32 + o0 + 1] * y1);
    float p1 = fmaf(rho_w2[1 * 32 + o0], y0, rho_w2[1 * 32 + o0 + 1] * y1);
#pragma unroll
    for (int m = 1; m < 16; m <<= 1) {
        p0 += __shfl_xor(p0, m);
        p1 += __shfl_xor(p1, m);
    }

    if (j == 0) {
        float2 r;
        r.x = fmaxf(p0 + rho_b2[0], 0.0f);
        r.y = fmaxf(p1 + rho_b2[1], 0.0f);
        reinterpret_cast<float2*>(out)[row] = r;
    }
}

extern "C" void kernel_launch(void* const* d_in, const int* in_sizes, int n_in,
                              void* d_out, int out_size, void* d_ws, size_t ws_size,
                              hipStream_t stream) {
    const float* x      = (const float*)d_in[0];
    const float* phi_w1 = (const float*)d_in[1];
    const float* phi_b1 = (const float*)d_in[2];
    const float* phi_w2 = (const float*)d_in[3];
    const float* phi_b2 = (const float*)d_in[4];
    const float* rho_w1 = (const float*)d_in[5];
    const float* rho_b1 = (const float*)d_in[6];
    const float* rho_w2 = (const float*)d_in[7];
    const float* rho_b2 = (const float*)d_in[8];
    float* out = (float*)d_out;

    const int threads = 256;
    const int total   = NDATA * NN;          // one thread per (row, neighbor)
    const int blocks  = total / threads;     // 16384, exact

    deepset_kernel<<<blocks, threads, 0, stream>>>(
        x, phi_w1, phi_b1, phi_w2, phi_b2,
        rho_w1, rho_b1, rho_w2, rho_b2, out);
}